// Round 14
// baseline (129.413 us; speedup 1.0000x reference)
//
#include <hip/hip_runtime.h>
#include <hip/hip_bf16.h>

typedef __attribute__((ext_vector_type(8))) short short8;
typedef __attribute__((ext_vector_type(4))) float f32x4;
typedef __attribute__((ext_vector_type(4))) unsigned int u32x4;

#define B_DIM   8192
#define IN_DIM  2048
#define OUT_DIM 1024

#define BM 256
#define BN 128
#define KS 64                      // K per tile
#define NT (IN_DIM / KS)           // 32 K-tiles
#define A_VAR_E (BM * KS)          // 16384 elems = 32 KB per variant (single-buffered)
#define B_TILE_E (BN * KS)         // 8192 elems = 16 KB (double-buffered)
#define LDS_BYTES ((2 * A_VAR_E + 2 * B_TILE_E) * 2)   // 98304 = 96 KiB

__device__ __forceinline__ unsigned short f2bf(float f) {
    union { float f; unsigned u; } v; v.f = f;
    unsigned u = v.u;
    unsigned r = (u + 0x7FFFu + ((u >> 16) & 1u)) >> 16;   // RNE
    return (unsigned short)r;
}

// Bw[o][i] = W[i][o]  (|W| derived in-register; 0.1 folded into A's na variant)
__global__ void prep_w(const float* __restrict__ W, unsigned short* __restrict__ Bw) {
    __shared__ float tile[32][33];
    int o0 = blockIdx.x * 32;
    int i0 = blockIdx.y * 32;
    int tx = threadIdx.x, ty = threadIdx.y;   // 32 x 8
    #pragma unroll
    for (int r = 0; r < 4; ++r) {
        int ii = ty + r * 8;
        tile[ii][tx] = W[(size_t)(i0 + ii) * OUT_DIM + o0 + tx];
    }
    __syncthreads();
    #pragma unroll
    for (int r = 0; r < 4; ++r) {
        int oo = ty + r * 8;
        Bw[(size_t)(o0 + oo) * IN_DIM + i0 + tx] = f2bf(tile[tx][oo]);
    }
}

// B staging: 128x64 tile = 16 KB = 2 rounds x (512 thr x 16 B). Linear LDS
// dest, XOR-swizzled global SOURCE slot (rule 21; R3-proven conflict-free).
__device__ __forceinline__ void stageB(const unsigned short* __restrict__ g,
                                       unsigned short* lds_dst,
                                       int col0, int k0, int tid) {
    #pragma unroll
    for (int r = 0; r < 2; ++r) {
        int c    = r * 512 + tid;
        int row  = c >> 3;                       // 0..127
        int slot = (c & 7) ^ (row & 7);
        __builtin_amdgcn_global_load_lds(
            (const __attribute__((address_space(1))) void*)(g + (size_t)(col0 + row) * IN_DIM + k0 + slot * 8),
            (__attribute__((address_space(3))) void*)(lds_dst + (size_t)c * 8),
            16, 0, 0);
    }
}

// x -> regs: thread covers row r_=tid>>1, k-half h=tid&1 (32 f32, 128 B
// contiguous; thread pairs cover 256 B rows -> coalesced).
__device__ __forceinline__ void issue_x(const float* __restrict__ x, float4* xv,
                                        int row0, int r_, int h, int kt) {
    const float4* p = reinterpret_cast<const float4*>(
        x + (size_t)(row0 + r_) * IN_DIM + kt * KS + h * 32);
    #pragma unroll
    for (int j = 0; j < 8; ++j) xv[j] = p[j];
}

// regs -> dual bf16 A variants (xm = mask(x)*x, na = -0.1|x|), 8-slot XOR
// swizzle (slot = (4h+q) ^ (row&7)); f32-exact mask (matches reference).
__device__ __forceinline__ void cvt_store(const float4* xv, unsigned short* sA,
                                          int r_, int h) {
    int sw = r_ & 7;
    #pragma unroll
    for (int q = 0; q < 4; ++q) {
        float4 va = xv[2 * q], vb = xv[2 * q + 1];
        float m0 = va.x >= -1.0f ? va.x : 0.0f;
        float m1 = va.y >= -1.0f ? va.y : 0.0f;
        float m2 = va.z >= -1.0f ? va.z : 0.0f;
        float m3 = va.w >= -1.0f ? va.w : 0.0f;
        float m4 = vb.x >= -1.0f ? vb.x : 0.0f;
        float m5 = vb.y >= -1.0f ? vb.y : 0.0f;
        float m6 = vb.z >= -1.0f ? vb.z : 0.0f;
        float m7 = vb.w >= -1.0f ? vb.w : 0.0f;
        float n0 = -0.1f * fabsf(va.x), n1 = -0.1f * fabsf(va.y);
        float n2 = -0.1f * fabsf(va.z), n3 = -0.1f * fabsf(va.w);
        float n4 = -0.1f * fabsf(vb.x), n5 = -0.1f * fabsf(vb.y);
        float n6 = -0.1f * fabsf(vb.z), n7 = -0.1f * fabsf(vb.w);
        unsigned dm[4], dn[4];
        asm("v_cvt_pk_bf16_f32 %0,%1,%2" : "=v"(dm[0]) : "v"(m0), "v"(m1));
        asm("v_cvt_pk_bf16_f32 %0,%1,%2" : "=v"(dm[1]) : "v"(m2), "v"(m3));
        asm("v_cvt_pk_bf16_f32 %0,%1,%2" : "=v"(dm[2]) : "v"(m4), "v"(m5));
        asm("v_cvt_pk_bf16_f32 %0,%1,%2" : "=v"(dm[3]) : "v"(m6), "v"(m7));
        asm("v_cvt_pk_bf16_f32 %0,%1,%2" : "=v"(dn[0]) : "v"(n0), "v"(n1));
        asm("v_cvt_pk_bf16_f32 %0,%1,%2" : "=v"(dn[1]) : "v"(n2), "v"(n3));
        asm("v_cvt_pk_bf16_f32 %0,%1,%2" : "=v"(dn[2]) : "v"(n4), "v"(n5));
        asm("v_cvt_pk_bf16_f32 %0,%1,%2" : "=v"(dn[3]) : "v"(n6), "v"(n7));
        int off = r_ * KS + (((h << 2) + q) ^ sw) * 8;
        *reinterpret_cast<u32x4*>(sA + off)           = (u32x4){dm[0], dm[1], dm[2], dm[3]};
        *reinterpret_cast<u32x4*>(sA + A_VAR_E + off) = (u32x4){dn[0], dn[1], dn[2], dn[3]};
    }
}

// fragment read (64-elem rows, 8 slots, R3-proven swizzle)
__device__ __forceinline__ short8 read_frag(const unsigned short* buf, int row,
                                            int kk, int lq) {
    int sl = ((kk << 2) + lq) ^ (row & 7);
    return *reinterpret_cast<const short8*>(buf + row * KS + (sl << 3));
}

#define MFMA16(AF, BF)                                                        \
    _Pragma("unroll") for (int m_ = 0; m_ < 4; ++m_)                          \
        _Pragma("unroll") for (int n_ = 0; n_ < 4; ++n_)                      \
            acc[m_][n_] = __builtin_amdgcn_mfma_f32_16x16x32_bf16(            \
                (AF)[m_], (BF)[n_], acc[m_][n_], 0, 0, 0)

#define PH_OPEN()  do { __builtin_amdgcn_s_barrier();                         \
    asm volatile("s_waitcnt lgkmcnt(0)" ::: "memory");                        \
    __builtin_amdgcn_sched_barrier(0);                                        \
    __builtin_amdgcn_s_setprio(1); } while (0)

// out[b][o] = sum_i [ mask(x)*x*W + (-0.1|x|)*|W| ] + 1e-5
// m201-style 4 fat phases (16 MFMA each) per K=64 tile; A single-buffered
// (write provably after all reads via ph3's opening barrier); counted vmcnt.
__global__ __launch_bounds__(512, 2) void gemm_fused(const float* __restrict__ x,
                                                     const unsigned short* __restrict__ Bw,
                                                     float* __restrict__ C) {
    extern __shared__ __align__(16) unsigned short smem[];
    unsigned short* sA  = smem;                       // [2 variants][16384]
    unsigned short* sB0 = smem + 2 * A_VAR_E;         // B buf 0
    unsigned short* sB1 = sB0 + B_TILE_E;             // B buf 1

    // XCD colocation (R3-verified): each XCD owns 4 contiguous by-panels
    int bid = blockIdx.x;
    int xcd = bid & 7;
    int idx = bid >> 3;            // 0..31
    int by  = xcd * 4 + (idx >> 3);
    int bx  = idx & 7;
    int row0 = by * BM;
    int col0 = bx * BN;

    int tid  = threadIdx.x;
    int lane = tid & 63;
    int w    = tid >> 6;           // 0..7
    int wr   = w >> 1;             // 0..3
    int wc   = w & 1;              // 0..1
    int lr   = lane & 15;
    int lq   = lane >> 4;          // 0..3
    int rowA = wr * 64 + lr;
    int rowB = wc * 64 + lr;
    int r_   = tid >> 1;           // A-staging row 0..255
    int h    = tid & 1;            // k-half

    f32x4 acc[4][4];
    #pragma unroll
    for (int m = 0; m < 4; ++m)
        #pragma unroll
        for (int n = 0; n < 4; ++n)
            acc[m][n] = (f32x4){0.f, 0.f, 0.f, 0.f};

    float4 xv[8];

    // prologue: B(0) DMA (pinned oldest); x(0)->xv; A(0)<-cvt(xv) (compiler
    // auto-drains x(0) AND B(0) as older); refill xv with x(1); keep x(1)
    // in flight across the barrier.
    stageB(Bw, sB0, col0, 0, tid);
    __builtin_amdgcn_sched_barrier(0);
    issue_x(x, xv, row0, r_, h, 0);
    cvt_store(xv, sA, r_, h);
    issue_x(x, xv, row0, r_, h, 1);
    asm volatile("s_waitcnt lgkmcnt(0)" ::: "memory");
    asm volatile("s_waitcnt vmcnt(8)" ::: "memory");   // B(0)+x(0) retired; x(1) in flight
    __builtin_amdgcn_s_barrier();

    #pragma unroll 1
    for (int T = 0; T < NT; ++T) {
        unsigned short* bcur = (T & 1) ? sB1 : sB0;
        unsigned short* bnxt = (T & 1) ? sB0 : sB1;
        bool dob = (T + 1 < NT);
        bool dox = (T + 2 < NT);

        short8 a0k0[4], a0k1[4], a1k0[4], a1k1[4], b0[4], b1[4], fb[4];

        // ---- ph1: read A0(kk0,kk1) + B(kk0); issue B(T+1) DMA; MFMA v0k0 ----
        #pragma unroll
        for (int m = 0; m < 4; ++m) {
            a0k0[m] = read_frag(sA, rowA + m * 16, 0, lq);
            a0k1[m] = read_frag(sA, rowA + m * 16, 1, lq);
        }
        #pragma unroll
        for (int n = 0; n < 4; ++n)
            b0[n] = read_frag(bcur, rowB + n * 16, 0, lq);
        if (dob) stageB(Bw, bnxt, col0, (T + 1) * KS, tid);
        __builtin_amdgcn_sched_barrier(0);     // pin B DMA older than x loads
        PH_OPEN();
        MFMA16(a0k0, b0);
        __builtin_amdgcn_s_setprio(0);
        __builtin_amdgcn_s_barrier();

        // ---- ph2: read A1(kk0,kk1); derive |W| kk0; MFMA v1k0 ----
        #pragma unroll
        for (int m = 0; m < 4; ++m) {
            a1k0[m] = read_frag(sA + A_VAR_E, rowA + m * 16, 0, lq);
            a1k1[m] = read_frag(sA + A_VAR_E, rowA + m * 16, 1, lq);
        }
        #pragma unroll
        for (int n = 0; n < 4; ++n) {
            u32x4 tb = *reinterpret_cast<u32x4*>(&b0[n]);
            tb = tb & 0x7FFF7FFFu;
            fb[n] = *reinterpret_cast<short8*>(&tb);
        }
        PH_OPEN();
        MFMA16(a1k0, fb);
        __builtin_amdgcn_s_setprio(0);
        __builtin_amdgcn_s_barrier();

        // ---- ph3: read B(kk1); MFMA v0k1; cvt_store A(T+1) (safe: after
        //      ph3's opening barrier all waves' A reads are complete) ----
        #pragma unroll
        for (int n = 0; n < 4; ++n)
            b1[n] = read_frag(bcur, rowB + n * 16, 1, lq);
        PH_OPEN();
        MFMA16(a0k1, b1);
        __builtin_amdgcn_s_setprio(0);
        if (dob) cvt_store(xv, sA, r_, h);     // consumes x(T+1)
        asm volatile("s_waitcnt lgkmcnt(0)" ::: "memory");   // writes visible
        __builtin_amdgcn_s_barrier();

        // ---- ph4: issue x(T+2); derive |W| kk1; MFMA v1k1; counted vmcnt ----
        if (dox) issue_x(x, xv, row0, r_, h, T + 2);
        #pragma unroll
        for (int n = 0; n < 4; ++n) {
            u32x4 tb = *reinterpret_cast<u32x4*>(&b1[n]);
            tb = tb & 0x7FFF7FFFu;
            fb[n] = *reinterpret_cast<short8*>(&tb);
        }
        PH_OPEN();
        MFMA16(a1k1, fb);
        __builtin_amdgcn_s_setprio(0);
        if (dob) {
            if (dox) asm volatile("s_waitcnt vmcnt(8)" ::: "memory");  // retire B(T+1), keep x(T+2)
            else     asm volatile("s_waitcnt vmcnt(0)" ::: "memory");
        }
        __builtin_amdgcn_s_barrier();
    }

    // epilogue: C/D layout col = lane&15, row = (lane>>4)*4 + reg
    #pragma unroll
    for (int m = 0; m < 4; ++m) {
        #pragma unroll
        for (int n = 0; n < 4; ++n) {
            int col  = col0 + wc * 64 + n * 16 + lr;
            int rowb = row0 + wr * 64 + m * 16 + lq * 4;
            #pragma unroll
            for (int j = 0; j < 4; ++j)
                C[(size_t)(rowb + j) * OUT_DIM + col] = acc[m][n][j] + 1e-5f;
        }
    }
}

extern "C" void kernel_launch(void* const* d_in, const int* in_sizes, int n_in,
                              void* d_out, int out_size, void* d_ws, size_t ws_size,
                              hipStream_t stream) {
    const float* x = (const float*)d_in[0];
    const float* W = (const float*)d_in[1];
    float* out = (float*)d_out;

    unsigned short* Bw = (unsigned short*)d_ws;    // 4 MB

    (void)hipFuncSetAttribute((const void*)gemm_fused,
                              hipFuncAttributeMaxDynamicSharedMemorySize, LDS_BYTES);

    prep_w<<<dim3(OUT_DIM / 32, IN_DIM / 32), dim3(32, 8), 0, stream>>>(W, Bw);
    gemm_fused<<<(B_DIM / BM) * (OUT_DIM / BN), 512, LDS_BYTES, stream>>>(x, Bw, out);
}

// Round 15
// 89.425 us; speedup vs baseline: 1.4472x; 1.4472x over previous
//
#include <hip/hip_runtime.h>
#include <hip/hip_bf16.h>

typedef __attribute__((ext_vector_type(8)))  short    short8;
typedef __attribute__((ext_vector_type(16))) float    f32x16;
typedef __attribute__((ext_vector_type(2)))  unsigned u32x2;
typedef __attribute__((ext_vector_type(4)))  unsigned u32x4;

#define B_DIM   8192
#define IN_DIM  2048
#define OUT_DIM 1024

#define BM 128
#define BN 128
#define KS 32                      // K per iteration (2 ksteps of 16)
#define NT (IN_DIM / KS)           // 64 iterations
// A buffer: [ma:4][kstep:2][var:2][lane:64][elem:8] = 8192 elems = 16 KB
#define A_BUF_E 8192
// B tile:   [ks:2][na:4][lane:64][elem:8] = 4096 elems = 8 KB
#define B_TILE_E 4096
#define LDS_BYTES ((2 * A_BUF_E + 2 * B_TILE_E) * 2)   // 49152 = 48 KiB

__device__ __forceinline__ unsigned short f2bf(float f) {
    union { float f; unsigned u; } v; v.f = f;
    unsigned u = v.u;
    unsigned r = (u + 0x7FFFu + ((u >> 16) & 1u)) >> 16;   // RNE
    return (unsigned short)r;
}

// Bw in FRAGMENT-LINEAR layout for mfma_32x32x16 B-operand:
//   elem (o, i) -> [bx=o>>7][ks=i>>4][na=(o>>5)&3][lane=((i>>3)&1)*32+(o&31)][e=i&7]
__global__ void prep_w(const float* __restrict__ W, unsigned short* __restrict__ Bw) {
    __shared__ float tile[32][33];
    int o0 = blockIdx.x * 32;
    int i0 = blockIdx.y * 32;
    int tx = threadIdx.x, ty = threadIdx.y;   // 32 x 8
    #pragma unroll
    for (int r = 0; r < 4; ++r) {
        int ii = ty + r * 8;
        tile[ii][tx] = W[(size_t)(i0 + ii) * OUT_DIM + o0 + tx];
    }
    __syncthreads();
    #pragma unroll
    for (int r = 0; r < 4; ++r) {
        int oo = ty + r * 8;
        int o = o0 + oo;
        int i = i0 + tx;
        size_t dst = ((((size_t)(o >> 7) * 128 + (i >> 4)) * 4 + ((o >> 5) & 3)) * 64
                      + ((i >> 3) & 1) * 32 + (o & 31)) * 8 + (i & 7);
        Bw[dst] = f2bf(tile[tx][oo]);
    }
}

// B staging: pure linear 8 KB DMA (global frag-linear -> LDS frag-linear).
__device__ __forceinline__ void stageB(const unsigned short* __restrict__ g,
                                       unsigned short* lds_dst,
                                       int bx, int kt, int tid) {
    const unsigned short* src = g + ((size_t)bx * 128 + 2 * kt) * 2048;
    #pragma unroll
    for (int r = 0; r < 2; ++r) {
        int c = r * 256 + tid;                // 0..511, 16 B each
        __builtin_amdgcn_global_load_lds(
            (const __attribute__((address_space(1))) void*)(src + (size_t)c * 8),
            (__attribute__((address_space(3))) void*)(lds_dst + (size_t)c * 8),
            16, 0, 0);
    }
}

// x -> regs, COALESCED (R13-proven): c = rnd*256+tid; 8 lanes cover one
// row's 32 f32 (128 B contiguous per 8-lane group).
__device__ __forceinline__ void issue_x4(const float* __restrict__ x, float4* xv,
                                         int row0, int tid, int kc) {
    #pragma unroll
    for (int rnd = 0; rnd < 4; ++rnd) {
        int c    = rnd * 256 + tid;
        int row  = c >> 3;                       // 0..127
        int col4 = c & 7;
        xv[rnd] = *reinterpret_cast<const float4*>(
            x + (size_t)(row0 + row) * IN_DIM + kc * KS + col4 * 4);
    }
}

// regs -> dual bf16 A variants, FRAGMENT-LINEAR:
//   elem (r, k) -> block (ma=r>>5)*4 + (ks=k>>4)*2 + v, lane=((k>>3)&1)*32+(r&31), e=k&7
// Thread (rnd): r = c>>3, k = (c&7)*4 .. +3  (4 elems -> one b64 write per variant)
__device__ __forceinline__ void cvt_store_dual(const float4* xv,
                                               unsigned short* Abuf, int tid) {
    #pragma unroll
    for (int rnd = 0; rnd < 4; ++rnd) {
        int c    = rnd * 256 + tid;
        int row  = c >> 3;
        int col4 = c & 7;
        int ma   = row >> 5;
        int ks   = col4 >> 2;
        int g    = (col4 >> 1) & 1;
        int lane = g * 32 + (row & 31);
        int eoff = ((ma * 2 + ks) * 2) * 512 + lane * 8 + (col4 & 1) * 4;
        float4 v = xv[rnd];
        float m0 = v.x >= -1.0f ? v.x : 0.0f;
        float m1 = v.y >= -1.0f ? v.y : 0.0f;
        float m2 = v.z >= -1.0f ? v.z : 0.0f;
        float m3 = v.w >= -1.0f ? v.w : 0.0f;
        float n0 = -0.1f * fabsf(v.x), n1 = -0.1f * fabsf(v.y);
        float n2 = -0.1f * fabsf(v.z), n3 = -0.1f * fabsf(v.w);
        unsigned xm0, xm1, na0, na1;
        asm("v_cvt_pk_bf16_f32 %0, %1, %2" : "=v"(xm0) : "v"(m0), "v"(m1));
        asm("v_cvt_pk_bf16_f32 %0, %1, %2" : "=v"(xm1) : "v"(m2), "v"(m3));
        asm("v_cvt_pk_bf16_f32 %0, %1, %2" : "=v"(na0) : "v"(n0), "v"(n1));
        asm("v_cvt_pk_bf16_f32 %0, %1, %2" : "=v"(na1) : "v"(n2), "v"(n3));
        *reinterpret_cast<u32x2*>(Abuf + eoff)       = (u32x2){xm0, xm1};   // var 0
        *reinterpret_cast<u32x2*>(Abuf + eoff + 512) = (u32x2){na0, na1};   // var 1
    }
}

// fragment reads: pure linear per lane (conflict-free by construction)
__device__ __forceinline__ short8 read_afrag(const unsigned short* buf,
                                             int ma, int ks, int v, int lane) {
    return *reinterpret_cast<const short8*>(buf + ((ma * 2 + ks) * 2 + v) * 512 + lane * 8);
}
__device__ __forceinline__ short8 read_bfrag(const unsigned short* buf,
                                             int na, int ks, int lane) {
    return *reinterpret_cast<const short8*>(buf + (ks * 4 + na) * 512 + lane * 8);
}

// one K=32 iteration, single barrier region (R13 cadence + queue discipline).
// Entry: x(t+1) in XCUR (4 loads outstanding). Issue: B(t+1) [2, pinned],
// x(t+2)->XNXT [4]. cvt_store(XCUR) compiler-waits x(t+1) (vmcnt<=6);
// manual: dox -> vmcnt(4) retires B(t+1), keeps x(t+2); else vmcnt(0).
#define ITER(T_, ACUR, ANXT, BCUR, BNXT, XCUR, XNXT) do {                     \
    int t_ = (T_);                                                            \
    bool dob_ = (t_ + 1 < NT);                                                \
    bool dox_ = (t_ + 2 < NT);                                                \
    if (dob_) stageB(Bw, (BNXT), bx, t_ + 1, tid);                            \
    __builtin_amdgcn_sched_barrier(0);   /* pin: B DMA oldest after x(t+1) */ \
    short8 fa[2][2][2], fb[2][2], fba[2][2];                                  \
    _Pragma("unroll") for (int m_ = 0; m_ < 2; ++m_)                          \
        _Pragma("unroll") for (int k_ = 0; k_ < 2; ++k_) {                    \
            fa[0][m_][k_] = read_afrag((ACUR), wr * 2 + m_, k_, 0, lane);     \
            fa[1][m_][k_] = read_afrag((ACUR), wr * 2 + m_, k_, 1, lane);     \
        }                                                                     \
    _Pragma("unroll") for (int n_ = 0; n_ < 2; ++n_)                          \
        _Pragma("unroll") for (int k_ = 0; k_ < 2; ++k_) {                    \
            fb[n_][k_] = read_bfrag((BCUR), wc * 2 + n_, k_, lane);           \
            u32x4 tb_ = *reinterpret_cast<u32x4*>(&fb[n_][k_]);               \
            tb_ = tb_ & 0x7FFF7FFFu;          /* |W| : clear bf16 sign bits */\
            fba[n_][k_] = *reinterpret_cast<short8*>(&tb_);                   \
        }                                                                     \
    if (dox_) issue_x4(x, (XNXT), row0, tid, t_ + 2);                         \
    __builtin_amdgcn_s_setprio(1);                                            \
    _Pragma("unroll") for (int m_ = 0; m_ < 2; ++m_)                          \
        _Pragma("unroll") for (int n_ = 0; n_ < 2; ++n_)                      \
            _Pragma("unroll") for (int k_ = 0; k_ < 2; ++k_) {                \
                acc[m_][n_] = __builtin_amdgcn_mfma_f32_32x32x16_bf16(        \
                    fa[0][m_][k_], fb[n_][k_], acc[m_][n_], 0, 0, 0);         \
                acc[m_][n_] = __builtin_amdgcn_mfma_f32_32x32x16_bf16(        \
                    fa[1][m_][k_], fba[n_][k_], acc[m_][n_], 0, 0, 0);        \
            }                                                                 \
    __builtin_amdgcn_s_setprio(0);                                            \
    if (dob_) {                                                               \
        cvt_store_dual((XCUR), (ANXT), tid);   /* x(t+1) -> A(t+1) */         \
        if (dox_) asm volatile("s_waitcnt vmcnt(4)" ::: "memory");            \
        else      asm volatile("s_waitcnt vmcnt(0)" ::: "memory");            \
        asm volatile("s_waitcnt lgkmcnt(0)" ::: "memory");                    \
        __builtin_amdgcn_s_barrier();                                         \
    }                                                                         \
} while (0)

// out[b][o] = sum_i [ mask(x)*x*W + (-0.1|x|)*|W| ] + 1e-5
__global__ __launch_bounds__(256, 2) void gemm_fused(const float* __restrict__ x,
                                                     const unsigned short* __restrict__ Bw,
                                                     float* __restrict__ C) {
    extern __shared__ __align__(16) unsigned short smem[];
    unsigned short* sA = smem;                    // [2][A_BUF_E]
    unsigned short* sB = smem + 2 * A_BUF_E;      // [2][B_TILE_E]

    // XCD colocation (R3-verified): same-by blocks share an XCD L2
    int bid = blockIdx.x;
    int xcd = bid & 7;
    int idx = bid >> 3;            // 0..63
    int by  = xcd * 8 + (idx >> 3);
    int bx  = idx & 7;
    int row0 = by * BM;
    int col0 = bx * BN;

    int tid  = threadIdx.x;
    int lane = tid & 63;
    int w    = tid >> 6;           // 0..3
    int wr   = w >> 1;             // 0..1 : 64-row half
    int wc   = w & 1;              // 0..1 : 64-col half

    f32x16 acc[2][2];
    #pragma unroll
    for (int m = 0; m < 2; ++m)
        #pragma unroll
        for (int n = 0; n < 2; ++n)
            #pragma unroll
            for (int j = 0; j < 16; ++j)
                acc[m][n][j] = 0.f;

    float4 xv0[4], xv1[4];

    // prologue (R13 queue shape): B(0) pinned oldest; x(0),x(1) issued;
    // A(0) <- cvt(xv0) (compiler waits x(0) => vmcnt<=4, B(0) older so
    // retired); manual vmcnt(4) keeps x(1) in flight.
    stageB(Bw, sB, bx, 0, tid);
    __builtin_amdgcn_sched_barrier(0);
    issue_x4(x, xv0, row0, tid, 0);
    issue_x4(x, xv1, row0, tid, 1);
    cvt_store_dual(xv0, sA, tid);
    asm volatile("s_waitcnt vmcnt(4)" ::: "memory");
    asm volatile("s_waitcnt lgkmcnt(0)" ::: "memory");
    __builtin_amdgcn_s_barrier();

    #pragma unroll 1
    for (int T = 0; T < NT; T += 2) {
        ITER(T,     sA,           sA + A_BUF_E, sB,            sB + B_TILE_E, xv1, xv0);
        ITER(T + 1, sA + A_BUF_E, sA,           sB + B_TILE_E, sB,            xv0, xv1);
    }

    // epilogue: 32x32 C/D layout (m74/m101-verified):
    //   col = lane&31, row = (reg&3) + 8*(reg>>2) + 4*(lane>>5)
    int l31 = lane & 31;
    int lh  = lane >> 5;
    #pragma unroll
    for (int m = 0; m < 2; ++m) {
        #pragma unroll
        for (int n = 0; n < 2; ++n) {
            int col   = col0 + wc * 64 + n * 32 + l31;
            int rbase = row0 + wr * 64 + m * 32 + 4 * lh;
            #pragma unroll
            for (int reg = 0; reg < 16; ++reg) {
                int row = rbase + (reg & 3) + 8 * (reg >> 2);
                C[(size_t)row * OUT_DIM + col] = acc[m][n][reg] + 1e-5f;
            }
        }
    }
}

extern "C" void kernel_launch(void* const* d_in, const int* in_sizes, int n_in,
                              void* d_out, int out_size, void* d_ws, size_t ws_size,
                              hipStream_t stream) {
    const float* x = (const float*)d_in[0];
    const float* W = (const float*)d_in[1];
    float* out = (float*)d_out;

    unsigned short* Bw = (unsigned short*)d_ws;    // 4 MB, fragment-linear

    (void)hipFuncSetAttribute((const void*)gemm_fused,
                              hipFuncAttributeMaxDynamicSharedMemorySize, LDS_BYTES);

    prep_w<<<dim3(OUT_DIM / 32, IN_DIM / 32), dim3(32, 8), 0, stream>>>(W, Bw);
    gemm_fused<<<(B_DIM / BM) * (OUT_DIM / BN), 256, LDS_BYTES, stream>>>(x, Bw, out);
}

// Round 16
// 85.396 us; speedup vs baseline: 1.5154x; 1.0472x over previous
//
#include <hip/hip_runtime.h>
#include <hip/hip_bf16.h>

typedef __attribute__((ext_vector_type(8))) short short8;
typedef __attribute__((ext_vector_type(4))) float f32x4;
typedef __attribute__((ext_vector_type(2))) unsigned u32x2;
typedef __attribute__((ext_vector_type(4))) unsigned u32x4;

#define B_DIM   8192
#define IN_DIM  2048
#define OUT_DIM 1024

#define BM 128
#define BN 128
#define KS 32                        // K per iteration
#define NT (IN_DIM / KS)             // 64 iterations (32 super-iters)
// A: per-wave private [4 waves][2 bufs][2 var][32 rows][32 k] = 32 KB total
#define A_WAVE_E (2 * 2 * 32 * 32)   // 4096 elems per wave
#define A_BUF_E  (2 * 32 * 32)       // 2048 elems per buf (2 var)
#define A_VAR_E  (32 * 32)           // 1024 elems per var
// B: [2 supers][2 tiles][128 rows][32 k] = 32 KB total
#define B_TILE_E (BN * KS)           // 4096 elems = 8 KB
#define B_SUP_E  (2 * B_TILE_E)
#define LDS_BYTES ((4 * A_WAVE_E + 2 * B_SUP_E) * 2)   // 65536 = 64 KiB

#define AS1 __attribute__((address_space(1)))
#define AS3 __attribute__((address_space(3)))

__device__ __forceinline__ unsigned short f2bf(float f) {
    union { float f; unsigned u; } v; v.f = f;
    unsigned u = v.u;
    unsigned r = (u + 0x7FFFu + ((u >> 16) & 1u)) >> 16;   // RNE
    return (unsigned short)r;
}

// Bw[o][i] = W[i][o]  (|W| derived in-register; 0.1 folded into A's na variant)
__global__ void prep_w(const float* __restrict__ W, unsigned short* __restrict__ Bw) {
    __shared__ float tile[32][33];
    int o0 = blockIdx.x * 32;
    int i0 = blockIdx.y * 32;
    int tx = threadIdx.x, ty = threadIdx.y;   // 32 x 8
    #pragma unroll
    for (int r = 0; r < 4; ++r) {
        int ii = ty + r * 8;
        tile[ii][tx] = W[(size_t)(i0 + ii) * OUT_DIM + o0 + tx];
    }
    __syncthreads();
    #pragma unroll
    for (int r = 0; r < 4; ++r) {
        int oo = ty + r * 8;
        Bw[(size_t)(o0 + oo) * IN_DIM + i0 + tx] = f2bf(tile[tx][oo]);
    }
}

// B super-stage: 2 consecutive K-tiles (16 KB), R13-proven per-tile swizzle
// (0 conflicts). Linear LDS dest; XOR-swizzled global SOURCE slot (rule 21).
__device__ __forceinline__ void stage_super(const unsigned short* __restrict__ g,
                                            unsigned short* dst,
                                            int col0, int k0, int tid) {
    #pragma unroll
    for (int tt = 0; tt < 2; ++tt)
        #pragma unroll
        for (int r = 0; r < 2; ++r) {
            int c    = r * 256 + tid;                // 0..511
            int row  = c >> 2;                       // 0..127
            int slot = (c & 3) ^ ((row >> 1) & 3);
            __builtin_amdgcn_global_load_lds(
                (const AS1 void*)(g + (size_t)(col0 + row) * IN_DIM + k0 + tt * KS + slot * 8),
                (AS3 void*)(dst + tt * B_TILE_E + (size_t)c * 8),
                16, 0, 0);
        }
}

// x -> regs, per-wave, COALESCED: rnd covers 8 rows x 32 f32 (8 lanes/row,
// 128 B contiguous per 8-lane group); 4 rnds cover the wave's 32 rows.
__device__ __forceinline__ void issue_x(const float* __restrict__ x, float4* xv,
                                        int rowW, int lane, int kc) {
    #pragma unroll
    for (int rnd = 0; rnd < 4; ++rnd) {
        int c    = rnd * 64 + lane;
        int row  = c >> 3;                       // 0..31
        int col4 = c & 7;
        xv[rnd] = *reinterpret_cast<const float4*>(
            x + (size_t)(rowW + row) * IN_DIM + kc * KS + col4 * 4);
    }
}

// regs -> dual bf16 A variants in this wave's PRIVATE region (R13 write
// pattern verbatim: measured 0 conflicts). No cross-wave visibility needed.
__device__ __forceinline__ void cvt_store(const float4* xv, unsigned short* Abuf,
                                          int lane) {
    #pragma unroll
    for (int rnd = 0; rnd < 4; ++rnd) {
        int c    = rnd * 64 + lane;
        int row  = c >> 3;
        int col4 = c & 7;
        int eoff = row * KS + ((col4 * 4) ^ (((row >> 1) & 3) * 8));
        float4 v = xv[rnd];
        float m0 = v.x >= -1.0f ? v.x : 0.0f;
        float m1 = v.y >= -1.0f ? v.y : 0.0f;
        float m2 = v.z >= -1.0f ? v.z : 0.0f;
        float m3 = v.w >= -1.0f ? v.w : 0.0f;
        float n0 = -0.1f * fabsf(v.x), n1 = -0.1f * fabsf(v.y);
        float n2 = -0.1f * fabsf(v.z), n3 = -0.1f * fabsf(v.w);
        unsigned xm0, xm1, na0, na1;
        asm("v_cvt_pk_bf16_f32 %0, %1, %2" : "=v"(xm0) : "v"(m0), "v"(m1));
        asm("v_cvt_pk_bf16_f32 %0, %1, %2" : "=v"(xm1) : "v"(m2), "v"(m3));
        asm("v_cvt_pk_bf16_f32 %0, %1, %2" : "=v"(na0) : "v"(n0), "v"(n1));
        asm("v_cvt_pk_bf16_f32 %0, %1, %2" : "=v"(na1) : "v"(n2), "v"(n3));
        *reinterpret_cast<u32x2*>(Abuf + eoff)           = (u32x2){xm0, xm1};
        *reinterpret_cast<u32x2*>(Abuf + A_VAR_E + eoff) = (u32x2){na0, na1};
    }
}

// fragment read, inverse swizzle (R13 verbatim): slot = lq ^ ((row>>1)&3)
__device__ __forceinline__ short8 read_frag(const unsigned short* buf, int row,
                                            int lq) {
    int sl = lq ^ ((row >> 1) & 3);
    return *reinterpret_cast<const short8*>(buf + row * KS + sl * 8);
}

// one iteration's compute: wave-private A (2 m-frags x 2 var), shared B
// (8 n-frags + in-reg |W|), 32 MFMA into acc[2][8]
#define COMPUTE(ABUF, BTILE) do {                                             \
    short8 fa0[2], fa1[2], fb[8], fba[8];                                     \
    _Pragma("unroll") for (int m_ = 0; m_ < 2; ++m_) {                        \
        fa0[m_] = read_frag((ABUF),           m_ * 16 + lr, lq);              \
        fa1[m_] = read_frag((ABUF) + A_VAR_E, m_ * 16 + lr, lq);              \
    }                                                                         \
    _Pragma("unroll") for (int n_ = 0; n_ < 8; ++n_) {                        \
        fb[n_] = read_frag((BTILE), n_ * 16 + lr, lq);                        \
        u32x4 tb_ = *reinterpret_cast<u32x4*>(&fb[n_]);                       \
        tb_ = tb_ & 0x7FFF7FFFu;              /* |W| : clear bf16 sign bits */\
        fba[n_] = *reinterpret_cast<short8*>(&tb_);                           \
    }                                                                         \
    __builtin_amdgcn_s_setprio(1);                                            \
    _Pragma("unroll") for (int m_ = 0; m_ < 2; ++m_)                          \
        _Pragma("unroll") for (int n_ = 0; n_ < 8; ++n_) {                    \
            acc[m_][n_] = __builtin_amdgcn_mfma_f32_16x16x32_bf16(            \
                fa0[m_], fb[n_],  acc[m_][n_], 0, 0, 0);                      \
            acc[m_][n_] = __builtin_amdgcn_mfma_f32_16x16x32_bf16(            \
                fa1[m_], fba[n_], acc[m_][n_], 0, 0, 0);                      \
        }                                                                     \
    __builtin_amdgcn_s_setprio(0);                                            \
} while (0)

// out[b][o] = sum_i [ mask(x)*x*W + (-0.1|x|)*|W| ] + 1e-5
// Wave-private A (no cross-wave barrier for A); barrier once per 2 iters
// (B super-buffer). Queue: B-super pinned oldest; x ping-pong depth 2;
// odd-iter cvt auto-retires B (in-order) before the barrier.
__global__ __launch_bounds__(256, 2) void gemm_fused(const float* __restrict__ x,
                                                     const unsigned short* __restrict__ Bw,
                                                     float* __restrict__ C) {
    extern __shared__ __align__(16) unsigned short smem[];
    unsigned short* sB = smem;                       // [2][B_SUP_E]
    unsigned short* sAall = smem + 2 * B_SUP_E;      // [4 waves][A_WAVE_E]

    // XCD colocation (R3-verified)
    int bid = blockIdx.x;
    int xcd = bid & 7;
    int idx = bid >> 3;            // 0..63
    int by  = xcd * 8 + (idx >> 3);
    int bx  = idx & 7;
    int row0 = by * BM;
    int col0 = bx * BN;

    int tid  = threadIdx.x;
    int lane = tid & 63;
    int w    = tid >> 6;           // 0..3 : wave owns rows [w*32, w*32+32)
    int lr   = lane & 15;
    int lq   = lane >> 4;          // 0..3
    int rowW = row0 + w * 32;      // this wave's global row base

    unsigned short* sA0 = sAall + w * A_WAVE_E;      // wave-private buf 0
    unsigned short* sA1 = sA0 + A_BUF_E;             // wave-private buf 1

    f32x4 acc[2][8];
    #pragma unroll
    for (int m = 0; m < 2; ++m)
        #pragma unroll
        for (int n = 0; n < 8; ++n)
            acc[m][n] = (f32x4){0.f, 0.f, 0.f, 0.f};

    float4 xvE[4], xvO[4];

    // prologue: super0 (tiles 0,1) pinned oldest; x(0)->xvE, x(1)->xvO;
    // A(0) <- cvt(xvE) (auto-retires super0 + x(0)); xvO stays in flight.
    stage_super(Bw, sB, col0, 0, tid);
    __builtin_amdgcn_sched_barrier(0);
    issue_x(x, xvE, rowW, lane, 0);
    issue_x(x, xvO, rowW, lane, 1);
    cvt_store(xvE, sA0, lane);
    asm volatile("s_waitcnt vmcnt(4)" ::: "memory");
    asm volatile("s_waitcnt lgkmcnt(0)" ::: "memory");
    __builtin_amdgcn_s_barrier();

    #pragma unroll 1
    for (int S = 0; S < NT / 2; ++S) {
        int t = 2 * S;
        unsigned short* bsup = sB + (S & 1) * B_SUP_E;
        unsigned short* bnxt = sB + ((S & 1) ^ 1) * B_SUP_E;
        bool dob = (t + 2 < NT);   // stage super S+1 (tiles t+2, t+3)
        bool dox3 = (t + 3 < NT);

        // ---- even iter t: B-super(S+1) pinned oldest; x(t+2)->xvE;
        //      compute A-buf0 x B-tile0; cvt x(t+1)->A-buf1; NO barrier ----
        if (dob) stage_super(Bw, bnxt, col0, (t + 2) * KS, tid);
        __builtin_amdgcn_sched_barrier(0);
        if (dob) issue_x(x, xvE, rowW, lane, t + 2);
        COMPUTE(sA0, bsup);
        cvt_store(xvO, sA1, lane);                 // x(t+1) -> A(t+1), private
        asm volatile("s_waitcnt lgkmcnt(0)" ::: "memory");   // own writes done

        // ---- odd iter t+1: x(t+3)->xvO; compute A-buf1 x B-tile1;
        //      cvt x(t+2)->A-buf0 (auto-retires B-super(S+1), it is oldest);
        //      counted vmcnt + barrier ----
        if (dox3) issue_x(x, xvO, rowW, lane, t + 3);
        COMPUTE(sA1, bsup + B_TILE_E);
        if (dob) cvt_store(xvE, sA0, lane);        // x(t+2) -> A(t+2), private
        if (dox3)     asm volatile("s_waitcnt vmcnt(4)" ::: "memory");
        else          asm volatile("s_waitcnt vmcnt(0)" ::: "memory");
        asm volatile("s_waitcnt lgkmcnt(0)" ::: "memory");
        __builtin_amdgcn_s_barrier();
    }

    // epilogue: C/D layout col = lane&15, row = (lane>>4)*4 + reg
    #pragma unroll
    for (int m = 0; m < 2; ++m) {
        #pragma unroll
        for (int n = 0; n < 8; ++n) {
            int col  = col0 + n * 16 + lr;
            int rowb = rowW + m * 16 + lq * 4;
            #pragma unroll
            for (int j = 0; j < 4; ++j)
                C[(size_t)(rowb + j) * OUT_DIM + col] = acc[m][n][j] + 1e-5f;
        }
    }
}

extern "C" void kernel_launch(void* const* d_in, const int* in_sizes, int n_in,
                              void* d_out, int out_size, void* d_ws, size_t ws_size,
                              hipStream_t stream) {
    const float* x = (const float*)d_in[0];
    const float* W = (const float*)d_in[1];
    float* out = (float*)d_out;

    unsigned short* Bw = (unsigned short*)d_ws;    // 4 MB

    (void)hipFuncSetAttribute((const void*)gemm_fused,
                              hipFuncAttributeMaxDynamicSharedMemorySize, LDS_BYTES);

    prep_w<<<dim3(OUT_DIM / 32, IN_DIM / 32), dim3(32, 8), 0, stream>>>(W, Bw);
    gemm_fused<<<(B_DIM / BM) * (OUT_DIM / BN), 256, LDS_BYTES, stream>>>(x, Bw, out);
}